// Round 2
// baseline (762.011 us; speedup 1.0000x reference)
//
#include <hip/hip_runtime.h>

#define S_LEN 2048
#define D_DIM 2048
#define NHEAD 32
#define NKVH  8
#define HDIM  64
#define NQKV  3072

typedef __attribute__((ext_vector_type(4))) float f32x4;
typedef __attribute__((ext_vector_type(8))) short bf16x8;

__device__ __forceinline__ unsigned short f2bf(float x) {
    union { float f; unsigned u; } v; v.f = x;
    unsigned r = v.u + 0x7FFFu + ((v.u >> 16) & 1u);
    return (unsigned short)(r >> 16);
}

// async global->LDS 16B: dest = wave-uniform base + lane*16
#define GLD(gsrc, ldst) __builtin_amdgcn_global_load_lds( \
    (const __attribute__((address_space(1))) unsigned int*)(const void*)(gsrc), \
    (__attribute__((address_space(3))) unsigned int*)(void*)(ldst), 16, 0, 0)

#define SWZ(r) (((r) & 7) << 4)

// ---------------- h -> bf16 ----------------
__global__ void k_cvt_h(const float* __restrict__ h, unsigned short* __restrict__ hb) {
    int i = (blockIdx.x * 256 + threadIdx.x) * 4;
    float4 v = *(const float4*)(h + i);
    ushort4 o;
    o.x = f2bf(v.x); o.y = f2bf(v.y); o.z = f2bf(v.z); o.w = f2bf(v.w);
    *(ushort4*)(hb + i) = o;
}

// ------------- transpose W [2048][N] f32 -> WT [N][2048] bf16 -------------
__global__ void k_transpose(const float* __restrict__ W, unsigned short* __restrict__ WT, int N) {
    __shared__ unsigned short L[64][65];
    int k0 = blockIdx.x * 64, n0 = blockIdx.y * 64;
    int t = threadIdx.x;
    for (int it = 0; it < 16; ++it) {
        int e = it * 256 + t;
        int r = e >> 6, c = e & 63;
        L[c][r] = f2bf(W[(size_t)(k0 + r) * N + n0 + c]);
    }
    __syncthreads();
    for (int it = 0; it < 16; ++it) {
        int e = it * 256 + t;
        int n = e >> 6, kk = e & 63;
        WT[(size_t)(n0 + n) * 2048 + k0 + kk] = L[n][kk];
    }
}

// ------------- transpose V slice of qkv -> vt [NKVH][64][S] bf16 -------------
__global__ void k_vtrans(const float* __restrict__ qkv, unsigned short* __restrict__ vt) {
    __shared__ unsigned short L[64][65];
    int s0 = blockIdx.x * 64, hk = blockIdx.y;
    int t = threadIdx.x;
    for (int it = 0; it < 16; ++it) {
        int e = it * 256 + t;
        int r = e >> 6, c = e & 63;
        L[c][r] = f2bf(qkv[(size_t)(s0 + r) * NQKV + 2560 + hk * 64 + c]);
    }
    __syncthreads();
    for (int it = 0; it < 16; ++it) {
        int e = it * 256 + t;
        int c = e >> 6, kk = e & 63;
        vt[((size_t)hk * 64 + c) * S_LEN + s0 + kk] = L[c][kk];
    }
}

// ---------------- adapter: field for 8 rows per block ----------------
__global__ __launch_bounds__(256) void k_field(const float* __restrict__ h, const float* __restrict__ Wf,
                        const float* __restrict__ W1, const float* __restrict__ b1,
                        const float* __restrict__ W2, const float* __restrict__ b2,
                        float* __restrict__ field) {
    __shared__ float hs[8][2080];
    __shared__ float red[256];
    __shared__ float hm[8][64];
    int s0 = blockIdx.x * 8;
    int t = threadIdx.x;
    // load 8 rows of h (f32, vectorized)
    for (int e4 = t; e4 < 4096; e4 += 256) {
        int r = e4 >> 9, i = (e4 & 511) * 4;
        *(float4*)&hs[r][i] = *(const float4*)&h[(size_t)(s0 + r) * D_DIM + i];
    }
    __syncthreads();
    // fiber: 8 rows x 16 outputs; 32 threads per row (16 f x 2 partials)
    {
        int r = t >> 5, f = t & 15, part = (t >> 4) & 1;
        float p = 0.f;
        for (int i = part * 1024; i < part * 1024 + 1024; ++i) p += hs[r][i] * Wf[i * 16 + f];
        p += __shfl_xor(p, 16);
        if (part == 0) hs[r][2048 + f] = p;
    }
    __syncthreads();
    // hmid rows
    for (int r = 0; r < 8; ++r) {
        int c = t & 63, part = t >> 6;
        float p = 0.f;
        for (int i = part; i < 2064; i += 4) p += hs[r][i] * W1[i * 64 + c];
        red[t] = p;
        __syncthreads();
        if (t < 64) {
            float x = red[t] + red[64 + t] + red[128 + t] + red[192 + t] + b1[t];
            hm[r][t] = 0.5f * x * (1.f + erff(x * 0.70710678118654752f));
        }
        __syncthreads();
    }
    // risk -> field: 32 threads per row
    {
        int r = t >> 5, l = t & 31;
        float p = hm[r][l] * W2[l] + hm[r][l + 32] * W2[l + 32];
        p += __shfl_xor(p, 1); p += __shfl_xor(p, 2); p += __shfl_xor(p, 4);
        p += __shfl_xor(p, 8); p += __shfl_xor(p, 16);
        if (l == 0) field[s0 + r] = 0.005f * (p + b2[0]);
    }
}

// ---------------- gate = (field - mean)/(std_ddof1 + 1e-6) ----------------
__global__ void k_gate(const float* __restrict__ field, float* __restrict__ gate) {
    __shared__ float red[256];
    int t = threadIdx.x;
    float s = 0.f;
    for (int i = t; i < S_LEN; i += 256) s += field[i];
    red[t] = s; __syncthreads();
    for (int w = 128; w; w >>= 1) { if (t < w) red[t] += red[t + w]; __syncthreads(); }
    float mean = red[0] / (float)S_LEN;
    __syncthreads();
    float v = 0.f;
    for (int i = t; i < S_LEN; i += 256) { float d = field[i] - mean; v += d * d; }
    red[t] = v; __syncthreads();
    for (int w = 128; w; w >>= 1) { if (t < w) red[t] += red[t + w]; __syncthreads(); }
    float stdv = sqrtf(red[0] / (float)(S_LEN - 1)) + 1e-6f;
    for (int i = t; i < S_LEN; i += 256) gate[i] = (field[i] - mean) / stdv;
}

// ------- bf16 MFMA GEMM (m97 structure): C[M][N] = A[M][K] * BT[N][K]^T -------
__global__ __launch_bounds__(256) void k_gemm(const unsigned short* __restrict__ A,
                                              const unsigned short* __restrict__ BT,
                                              float* __restrict__ C, int M, int N, int K) {
    __shared__ __align__(16) char As[8192];
    __shared__ __align__(16) char Bs[8192];
    int m0 = blockIdx.y * 128, n0 = blockIdx.x * 128;
    int t = threadIdx.x;
    int wv = t >> 6, ln = t & 63;
    int wr = (wv >> 1) * 64, wc = (wv & 1) * 64;
    int lr = ln & 15, lkb = (ln >> 4) * 16;   // frag k byte offset
    f32x4 acc[4][4] = {};
    const unsigned short* Ap = A + (size_t)(m0 + (t >> 2)) * K + (t & 3) * 8;
    const unsigned short* Bp = BT + (size_t)(n0 + (t >> 2)) * K + (t & 3) * 8;
    char* lA = As + wv * 1024;
    char* lB = Bs + wv * 1024;
    int nk = K / 32;
    // prologue
    GLD(Ap, lA); GLD(Ap + (size_t)64 * K, lA + 4096);
    GLD(Bp, lB); GLD(Bp + (size_t)64 * K, lB + 4096);
    for (int kt = 0; kt < nk; ++kt) {
        __syncthreads();   // loads for kt landed (vmcnt drained at barrier)
        bf16x8 af[4], bfv[4];
#pragma unroll
        for (int i = 0; i < 4; ++i) af[i]  = *(const bf16x8*)(As + (wr + i * 16 + lr) * 64 + lkb);
#pragma unroll
        for (int j = 0; j < 4; ++j) bfv[j] = *(const bf16x8*)(Bs + (wc + j * 16 + lr) * 64 + lkb);
#pragma unroll
        for (int i = 0; i < 4; ++i)
#pragma unroll
            for (int j = 0; j < 4; ++j)
                acc[i][j] = __builtin_amdgcn_mfma_f32_16x16x32_bf16(af[i], bfv[j], acc[i][j], 0, 0, 0);
        __syncthreads();   // all waves done reading
        if (kt + 1 < nk) {
            const unsigned short* Ak = Ap + (size_t)(kt + 1) * 32;
            const unsigned short* Bk = Bp + (size_t)(kt + 1) * 32;
            GLD(Ak, lA); GLD(Ak + (size_t)64 * K, lA + 4096);
            GLD(Bk, lB); GLD(Bk + (size_t)64 * K, lB + 4096);
        }
    }
    int orow = (ln >> 4) * 4;
#pragma unroll
    for (int i = 0; i < 4; ++i)
#pragma unroll
        for (int j = 0; j < 4; ++j) {
            float* Cp = C + (size_t)(m0 + wr + i * 16 + orow) * N + n0 + wc + j * 16 + lr;
            for (int r = 0; r < 4; ++r) Cp[(size_t)r * N] = acc[i][j][r];
        }
}

// ---------------- RoPE for q,k only (q prescaled by 1/8) ----------------
__global__ void k_rope(const float* __restrict__ qkv, const float* __restrict__ cs,
                       const float* __restrict__ sn,
                       unsigned short* __restrict__ qb, unsigned short* __restrict__ kb) {
    int s = blockIdx.x;
    const float* row = qkv + (size_t)s * NQKV;
    int t = threadIdx.x;
    for (int e = t; e < 2560; e += 256) {
        int d = e & 63;
        float val = row[e];
        float c = cs[s * 64 + d], si = sn[s * 64 + d];
        float partner = (d < 32) ? -row[e + 32] : row[e - 32];
        float out = val * c + partner * si;
        if (e < 2048) {
            qb[((size_t)(e >> 6) * S_LEN + s) * 64 + d] = f2bf(out * 0.125f);
        } else {
            kb[((size_t)((e - 2048) >> 6) * S_LEN + s) * 64 + d] = f2bf(out);
        }
    }
}

// ------- flash attention: 4 waves, 32 q-rows/wave, KVBLK=64, swizzled LDS -------
__global__ __launch_bounds__(256, 2) void k_attn(const unsigned short* __restrict__ qb,
                                                 const unsigned short* __restrict__ kb,
                                                 const unsigned short* __restrict__ vt,
                                                 const float* __restrict__ gate,
                                                 const float* __restrict__ gs_p,
                                                 unsigned short* __restrict__ attnout) {
    __shared__ __align__(16) char Kl[2][8192];   // [buf][64 k rows x 128B], read-swizzled
    __shared__ __align__(16) char Vl[2][8192];   // [buf][64 d rows x 128B]
    __shared__ __align__(16) char Pl[4][4096];   // per-wave [32 q x 128B]
    int qbi = 15 - blockIdx.x;                   // descending: big blocks first
    int h = blockIdx.y, hk = h >> 2;
    int t = threadIdx.x, wv = t >> 6, l = t & 63;
    int lr = l & 15, lg = l >> 4;
    float gs = gs_p[0];
    // Q fragments in registers
    const unsigned short* qbase = qb + ((size_t)h * S_LEN + qbi * 128 + wv * 32) * 64;
    bf16x8 aq[2][2];
#pragma unroll
    for (int rt = 0; rt < 2; ++rt)
#pragma unroll
        for (int hf = 0; hf < 2; ++hf)
            aq[rt][hf] = *(const bf16x8*)(qbase + (rt * 16 + lr) * 64 + hf * 32 + lg * 8);
    f32x4 o[2][4] = {};
    float m_[2][4], ls_[2][4];
#pragma unroll
    for (int rt = 0; rt < 2; ++rt)
        for (int r = 0; r < 4; ++r) { m_[rt][r] = -INFINITY; ls_[rt][r] = 0.f; }
    int nkt = 2 * qbi + 2;
    int mykt = (qbi * 128 + wv * 32 + 31) >> 6;  // last kt this wave computes
    // staging source (pre-swizzled so linear LDS dest + swizzled reads agree)
    int srow = t >> 3;
    int scol = 8 * ((t & 7) ^ (srow & 7));       // elements
    const unsigned short* kg = kb + (size_t)hk * S_LEN * 64;
    const unsigned short* vg = vt + (size_t)hk * 64 * S_LEN;
    char* lKb0 = Kl[0] + wv * 1024; char* lKb1 = Kl[1] + wv * 1024;
    char* lVb0 = Vl[0] + wv * 1024; char* lVb1 = Vl[1] + wv * 1024;
    {   // stage kt=0
        GLD(kg + (size_t)srow * 64 + scol, lKb0);
        GLD(kg + (size_t)(32 + srow) * 64 + scol, lKb0 + 4096);
        GLD(vg + (size_t)srow * S_LEN + scol, lVb0);
        GLD(vg + (size_t)(32 + srow) * S_LEN + scol, lVb0 + 4096);
    }
    for (int kt = 0; kt < nkt; ++kt) {
        __syncthreads();   // buf[kt&1] ready; prior reads of buf[(kt+1)&1] done
        if (kt + 1 < nkt) {
            int k0n = (kt + 1) * 64;
            char* lK = ((kt + 1) & 1) ? lKb1 : lKb0;
            char* lV = ((kt + 1) & 1) ? lVb1 : lVb0;
            GLD(kg + (size_t)(k0n + srow) * 64 + scol, lK);
            GLD(kg + (size_t)(k0n + 32 + srow) * 64 + scol, lK + 4096);
            GLD(vg + (size_t)srow * S_LEN + k0n + scol, lV);
            GLD(vg + (size_t)(32 + srow) * S_LEN + k0n + scol, lV + 4096);
        }
        if (kt <= mykt) {
            int buf = kt & 1, k0 = kt * 64;
            const char* Kb = Kl[buf];
            const char* Vb = Vl[buf];
            char* Pb = Pl[wv];
            // ---- QK^T ----
            f32x4 sc[2][4] = {};
#pragma unroll
            for (int ct = 0; ct < 4; ++ct) {
                int krow = ct * 16 + lr;
#pragma unroll
                for (int hf = 0; hf < 2; ++hf) {
                    bf16x8 bk = *(const bf16x8*)(Kb + krow * 128 + ((hf * 64 + lg * 16) ^ SWZ(krow)));
#pragma unroll
                    for (int rt = 0; rt < 2; ++rt)
                        sc[rt][ct] = __builtin_amdgcn_mfma_f32_16x16x32_bf16(aq[rt][hf], bk, sc[rt][ct], 0, 0, 0);
                }
            }
            // ---- softmax (online) + P write + O rescale ----
            float gb[4]; int kp[4];
#pragma unroll
            for (int ct = 0; ct < 4; ++ct) {
                kp[ct] = k0 + ct * 16 + lr;
                gb[ct] = gs * gate[kp[ct]];
            }
#pragma unroll
            for (int rt = 0; rt < 2; ++rt) {
#pragma unroll
                for (int r = 0; r < 4; ++r) {
                    int q = qbi * 128 + wv * 32 + rt * 16 + lg * 4 + r;
                    float pv[4], vmax = -INFINITY;
#pragma unroll
                    for (int ct = 0; ct < 4; ++ct) {
                        float val = sc[rt][ct][r] + gb[ct];
                        if (kp[ct] > q) val -= 1e9f;
                        pv[ct] = val;
                        vmax = fmaxf(vmax, val);
                    }
                    vmax = fmaxf(vmax, __shfl_xor(vmax, 1));
                    vmax = fmaxf(vmax, __shfl_xor(vmax, 2));
                    vmax = fmaxf(vmax, __shfl_xor(vmax, 4));
                    vmax = fmaxf(vmax, __shfl_xor(vmax, 8));
                    float mn = fmaxf(m_[rt][r], vmax);
                    float scl = __expf(m_[rt][r] - mn);
                    float rs = 0.f;
#pragma unroll
                    for (int ct = 0; ct < 4; ++ct) {
                        float p = __expf(pv[ct] - mn);
                        pv[ct] = p; rs += p;
                    }
                    rs += __shfl_xor(rs, 1); rs += __shfl_xor(rs, 2);
                    rs += __shfl_xor(rs, 4); rs += __shfl_xor(rs, 8);
                    ls_[rt][r] = ls_[rt][r] * scl + rs;
                    m_[rt][r] = mn;
#pragma unroll
                    for (int dt = 0; dt < 4; ++dt) o[rt][dt][r] *= scl;
                    int qloc = rt * 16 + lg * 4 + r;
#pragma unroll
                    for (int ct = 0; ct < 4; ++ct)
                        *(unsigned short*)(Pb + qloc * 128 + (((ct * 16 + lr) * 2) ^ SWZ(qloc))) = f2bf(pv[ct]);
                }
            }
            // ---- PV ---- (same-wave LDS write->read is in-order)
#pragma unroll
            for (int ks = 0; ks < 2; ++ks) {
                bf16x8 pa[2];
#pragma unroll
                for (int rt = 0; rt < 2; ++rt) {
                    int qrow = rt * 16 + lr;
                    pa[rt] = *(const bf16x8*)(Pb + qrow * 128 + ((ks * 64 + lg * 16) ^ SWZ(qrow)));
                }
#pragma unroll
                for (int dt = 0; dt < 4; ++dt) {
                    int vrow = dt * 16 + lr;
                    bf16x8 bv = *(const bf16x8*)(Vb + vrow * 128 + ((ks * 64 + lg * 16) ^ SWZ(vrow)));
#pragma unroll
                    for (int rt = 0; rt < 2; ++rt)
                        o[rt][dt] = __builtin_amdgcn_mfma_f32_16x16x32_bf16(pa[rt], bv, o[rt][dt], 0, 0, 0);
                }
            }
        }
    }
    // epilogue
#pragma unroll
    for (int rt = 0; rt < 2; ++rt)
#pragma unroll
        for (int r = 0; r < 4; ++r) {
            float inv = 1.f / ls_[rt][r];
            unsigned short* orow = attnout + (size_t)(qbi * 128 + wv * 32 + rt * 16 + lg * 4 + r) * 2048 + h * 64;
#pragma unroll
            for (int dt = 0; dt < 4; ++dt) orow[dt * 16 + lr] = f2bf(o[rt][dt][r] * inv);
        }
}

extern "C" void kernel_launch(void* const* d_in, const int* in_sizes, int n_in,
                              void* d_out, int out_size, void* d_ws, size_t ws_size,
                              hipStream_t stream) {
    const float* h    = (const float*)d_in[0];
    const float* cosT = (const float*)d_in[2];
    const float* sinT = (const float*)d_in[3];
    const float* Wf   = (const float*)d_in[4];
    const float* W1   = (const float*)d_in[5];
    const float* b1   = (const float*)d_in[6];
    const float* W2   = (const float*)d_in[7];
    const float* b2   = (const float*)d_in[8];
    const float* gs   = (const float*)d_in[9];
    const float* Wq   = (const float*)d_in[10];
    const float* Wk   = (const float*)d_in[11];
    const float* Wv   = (const float*)d_in[12];
    const float* Wo   = (const float*)d_in[13];
    float* out = (float*)d_out;

    char* ws = (char*)d_ws;
    unsigned short* hb    = (unsigned short*)(ws);                       // 8 MiB
    unsigned short* wqkv  = (unsigned short*)(ws + 8388608);             // 12 MiB
    unsigned short* wot   = (unsigned short*)(ws + 20971520);            // 8 MiB
    float*          qkv   = (float*)(ws + 29360128);                     // 24 MiB
    float*          field = (float*)(ws + 54525952);
    float*          gate  = (float*)(ws + 54534144);
    unsigned short* qbuf    = (unsigned short*)(ws + 8388608);           // over wqkv
    unsigned short* kbuf    = (unsigned short*)(ws + 16777216);
    unsigned short* vt      = (unsigned short*)(ws + 18874368);
    unsigned short* attnout = (unsigned short*)(ws);                     // over hb

    k_cvt_h<<<dim3(4096), dim3(256), 0, stream>>>(h, hb);
    k_transpose<<<dim3(32, 32), dim3(256), 0, stream>>>(Wq, wqkv, 2048);
    k_transpose<<<dim3(32, 8),  dim3(256), 0, stream>>>(Wk, wqkv + (size_t)2048 * 2048, 512);
    k_transpose<<<dim3(32, 8),  dim3(256), 0, stream>>>(Wv, wqkv + (size_t)2560 * 2048, 512);
    k_transpose<<<dim3(32, 32), dim3(256), 0, stream>>>(Wo, wot, 2048);
    k_field<<<dim3(256), dim3(256), 0, stream>>>(h, Wf, W1, b1, W2, b2, field);
    k_gate<<<dim3(1), dim3(256), 0, stream>>>(field, gate);
    k_gemm<<<dim3(24, 16), dim3(256), 0, stream>>>(hb, wqkv, qkv, 2048, 3072, 2048);
    k_rope<<<dim3(2048), dim3(256), 0, stream>>>(qkv, cosT, sinT, qbuf, kbuf);
    k_vtrans<<<dim3(32, 8), dim3(256), 0, stream>>>(qkv, vt);
    k_attn<<<dim3(16, 32), dim3(256), 0, stream>>>(qbuf, kbuf, vt, gate, gs, attnout);
    k_gemm<<<dim3(16, 16), dim3(256), 0, stream>>>(attnout, wot, out, 2048, 2048, 2048);
}

// Round 3
// 262.500 us; speedup vs baseline: 2.9029x; 2.9029x over previous
//
#include <hip/hip_runtime.h>

#define S_LEN 2048
#define D_DIM 2048
#define NHEAD 32
#define NKVH  8
#define HDIM  64
#define NBT   3200   // 2048 q + 512 k + 512 v + 16 fiber + 64 w1h + 48 pad

typedef __attribute__((ext_vector_type(4))) float f32x4;
typedef __attribute__((ext_vector_type(8))) short bf16x8;

__device__ __forceinline__ unsigned short f2bf(float x) {
    union { float f; unsigned u; } v; v.f = x;
    unsigned r = v.u + 0x7FFFu + ((v.u >> 16) & 1u);
    return (unsigned short)(r >> 16);
}

// async global->LDS 16B: dest = wave-uniform base + lane*16
#define GLD(gsrc, ldst) __builtin_amdgcn_global_load_lds( \
    (const __attribute__((address_space(1))) unsigned int*)(const void*)(gsrc), \
    (__attribute__((address_space(3))) unsigned int*)(void*)(ldst), 16, 0, 0)

#define SWZ(r) (((r) & 7) << 4)

// ---------------- h -> bf16 ----------------
__global__ void k_cvt_h(const float* __restrict__ h, unsigned short* __restrict__ hb) {
    int i = (blockIdx.x * 256 + threadIdx.x) * 4;
    float4 v = *(const float4*)(h + i);
    ushort4 o;
    o.x = f2bf(v.x); o.y = f2bf(v.y); o.z = f2bf(v.z); o.w = f2bf(v.w);
    *(ushort4*)(hb + i) = o;
}

// ------------- transpose W [2048][N] f32 -> WT [N][2048] bf16 -------------
__global__ void k_transpose(const float* __restrict__ W, unsigned short* __restrict__ WT, int N) {
    __shared__ unsigned short L[64][65];
    int k0 = blockIdx.x * 64, n0 = blockIdx.y * 64;
    int t = threadIdx.x;
    for (int it = 0; it < 16; ++it) {
        int e = it * 256 + t;
        int r = e >> 6, c = e & 63;
        L[c][r] = f2bf(W[(size_t)(k0 + r) * N + n0 + c]);
    }
    __syncthreads();
    for (int it = 0; it < 16; ++it) {
        int e = it * 256 + t;
        int n = e >> 6, kk = e & 63;
        WT[(size_t)(n0 + n) * 2048 + k0 + kk] = L[n][kk];
    }
}

// ------------- transpose Wf [2048][16] f32 -> WT [16][2048] bf16 -------------
__global__ void k_transpose16(const float* __restrict__ W, unsigned short* __restrict__ WT) {
    __shared__ unsigned short L[16][65];
    int k0 = blockIdx.x * 64;
    int t = threadIdx.x;
    for (int it = 0; it < 4; ++it) {
        int e = it * 256 + t;
        int r = e >> 4, c = e & 15;
        L[c][r] = f2bf(W[(size_t)(k0 + r) * 16 + c]);
    }
    __syncthreads();
    for (int it = 0; it < 4; ++it) {
        int e = it * 256 + t;
        int c = e >> 6, kk = e & 63;
        WT[(size_t)c * 2048 + k0 + kk] = L[c][kk];
    }
}

// ------------- transpose V slice of qkv -> vt [NKVH][64][S] bf16 -------------
__global__ void k_vtrans(const float* __restrict__ qkv, unsigned short* __restrict__ vt) {
    __shared__ unsigned short L[64][65];
    int s0 = blockIdx.x * 64, hk = blockIdx.y;
    int t = threadIdx.x;
    for (int it = 0; it < 16; ++it) {
        int e = it * 256 + t;
        int r = e >> 6, c = e & 63;
        L[c][r] = f2bf(qkv[(size_t)(s0 + r) * NBT + 2560 + hk * 64 + c]);
    }
    __syncthreads();
    for (int it = 0; it < 16; ++it) {
        int e = it * 256 + t;
        int c = e >> 6, kk = e & 63;
        vt[((size_t)hk * 64 + c) * S_LEN + s0 + kk] = L[c][kk];
    }
}

// ---- fuse: field[s] from fused GEMM cols (fiber 3072..3087, w1h 3088..3151) ----
__global__ __launch_bounds__(256) void k_fuse(const float* __restrict__ qkv,
                        const float* __restrict__ W1, const float* __restrict__ b1,
                        const float* __restrict__ W2, const float* __restrict__ b2,
                        float* __restrict__ field) {
    int wv = threadIdx.x >> 6, l = threadIdx.x & 63;
    int s = blockIdx.x * 4 + wv;
    const float* row = qkv + (size_t)s * NBT;
    float x = row[3088 + l] + b1[l];
#pragma unroll
    for (int f = 0; f < 16; ++f) x += row[3072 + f] * W1[(size_t)(2048 + f) * 64 + l];
    float hm = 0.5f * x * (1.f + erff(x * 0.70710678118654752f));
    float p = hm * W2[l];
    for (int m = 32; m; m >>= 1) p += __shfl_xor(p, m);
    if (l == 0) field[s] = 0.005f * (p + b2[0]);
}

// ---------------- gate = (field - mean)/(std_ddof1 + 1e-6) ----------------
__global__ void k_gate(const float* __restrict__ field, float* __restrict__ gate) {
    __shared__ float red[256];
    int t = threadIdx.x;
    float s = 0.f;
    for (int i = t; i < S_LEN; i += 256) s += field[i];
    red[t] = s; __syncthreads();
    for (int w = 128; w; w >>= 1) { if (t < w) red[t] += red[t + w]; __syncthreads(); }
    float mean = red[0] / (float)S_LEN;
    __syncthreads();
    float v = 0.f;
    for (int i = t; i < S_LEN; i += 256) { float d = field[i] - mean; v += d * d; }
    red[t] = v; __syncthreads();
    for (int w = 128; w; w >>= 1) { if (t < w) red[t] += red[t + w]; __syncthreads(); }
    float stdv = sqrtf(red[0] / (float)(S_LEN - 1)) + 1e-6f;
    for (int i = t; i < S_LEN; i += 256) gate[i] = (field[i] - mean) / stdv;
}

// ------- bf16 MFMA GEMM (m97 structure): C[M][N] = A[M][K] * BT[N][K]^T -------
__global__ __launch_bounds__(256) void k_gemm(const unsigned short* __restrict__ A,
                                              const unsigned short* __restrict__ BT,
                                              float* __restrict__ C, int M, int N, int K) {
    __shared__ __align__(16) char As[8192];
    __shared__ __align__(16) char Bs[8192];
    int m0 = blockIdx.y * 128, n0 = blockIdx.x * 128;
    int t = threadIdx.x;
    int wv = t >> 6, ln = t & 63;
    int wr = (wv >> 1) * 64, wc = (wv & 1) * 64;
    int lr = ln & 15, lkb = (ln >> 4) * 16;
    f32x4 acc[4][4] = {};
    const unsigned short* Ap = A + (size_t)(m0 + (t >> 2)) * K + (t & 3) * 8;
    const unsigned short* Bp = BT + (size_t)(n0 + (t >> 2)) * K + (t & 3) * 8;
    char* lA = As + wv * 1024;
    char* lB = Bs + wv * 1024;
    int nk = K / 32;
    GLD(Ap, lA); GLD(Ap + (size_t)64 * K, lA + 4096);
    GLD(Bp, lB); GLD(Bp + (size_t)64 * K, lB + 4096);
    for (int kt = 0; kt < nk; ++kt) {
        __syncthreads();
        bf16x8 af[4], bfv[4];
#pragma unroll
        for (int i = 0; i < 4; ++i) af[i]  = *(const bf16x8*)(As + (wr + i * 16 + lr) * 64 + lkb);
#pragma unroll
        for (int j = 0; j < 4; ++j) bfv[j] = *(const bf16x8*)(Bs + (wc + j * 16 + lr) * 64 + lkb);
#pragma unroll
        for (int i = 0; i < 4; ++i)
#pragma unroll
            for (int j = 0; j < 4; ++j)
                acc[i][j] = __builtin_amdgcn_mfma_f32_16x16x32_bf16(af[i], bfv[j], acc[i][j], 0, 0, 0);
        __syncthreads();
        if (kt + 1 < nk) {
            const unsigned short* Ak = Ap + (size_t)(kt + 1) * 32;
            const unsigned short* Bk = Bp + (size_t)(kt + 1) * 32;
            GLD(Ak, lA); GLD(Ak + (size_t)64 * K, lA + 4096);
            GLD(Bk, lB); GLD(Bk + (size_t)64 * K, lB + 4096);
        }
    }
    int orow = (ln >> 4) * 4;
#pragma unroll
    for (int i = 0; i < 4; ++i)
#pragma unroll
        for (int j = 0; j < 4; ++j) {
            float* Cp = C + (size_t)(m0 + wr + i * 16 + orow) * N + n0 + wc + j * 16 + lr;
            for (int r = 0; r < 4; ++r) Cp[(size_t)r * N] = acc[i][j][r];
        }
}

// ---------------- RoPE for q,k only (q prescaled by 1/8) ----------------
__global__ void k_rope(const float* __restrict__ qkv, const float* __restrict__ cs,
                       const float* __restrict__ sn,
                       unsigned short* __restrict__ qb, unsigned short* __restrict__ kb) {
    int s = blockIdx.x;
    const float* row = qkv + (size_t)s * NBT;
    int t = threadIdx.x;
    for (int e = t; e < 2560; e += 256) {
        int d = e & 63;
        float val = row[e];
        float c = cs[s * 64 + d], si = sn[s * 64 + d];
        float partner = (d < 32) ? -row[e + 32] : row[e - 32];
        float out = val * c + partner * si;
        if (e < 2048) {
            qb[((size_t)(e >> 6) * S_LEN + s) * 64 + d] = f2bf(out * 0.125f);
        } else {
            kb[((size_t)((e - 2048) >> 6) * S_LEN + s) * 64 + d] = f2bf(out);
        }
    }
}

// ------- flash attention: 4 waves, 32 q-rows/wave, KVBLK=64, swizzled LDS -------
__global__ __launch_bounds__(256, 2) void k_attn(const unsigned short* __restrict__ qb,
                                                 const unsigned short* __restrict__ kb,
                                                 const unsigned short* __restrict__ vt,
                                                 const float* __restrict__ gate,
                                                 const float* __restrict__ gs_p,
                                                 unsigned short* __restrict__ attnout) {
    __shared__ __align__(16) char Kl[2][8192];
    __shared__ __align__(16) char Vl[2][8192];
    __shared__ __align__(16) char Pl[4][4096];
    int qbi = 15 - blockIdx.x;
    int h = blockIdx.y, hk = h >> 2;
    int t = threadIdx.x, wv = t >> 6, l = t & 63;
    int lr = l & 15, lg = l >> 4;
    float gs = gs_p[0];
    const unsigned short* qbase = qb + ((size_t)h * S_LEN + qbi * 128 + wv * 32) * 64;
    bf16x8 aq[2][2];
#pragma unroll
    for (int rt = 0; rt < 2; ++rt)
#pragma unroll
        for (int hf = 0; hf < 2; ++hf)
            aq[rt][hf] = *(const bf16x8*)(qbase + (rt * 16 + lr) * 64 + hf * 32 + lg * 8);
    f32x4 o[2][4] = {};
    float m_[2][4], ls_[2][4];
#pragma unroll
    for (int rt = 0; rt < 2; ++rt)
        for (int r = 0; r < 4; ++r) { m_[rt][r] = -INFINITY; ls_[rt][r] = 0.f; }
    int nkt = 2 * qbi + 2;
    int mykt = (qbi * 128 + wv * 32 + 31) >> 6;
    int srow = t >> 3;
    int scol = 8 * ((t & 7) ^ (srow & 7));
    const unsigned short* kg = kb + (size_t)hk * S_LEN * 64;
    const unsigned short* vg = vt + (size_t)hk * 64 * S_LEN;
    char* lKb0 = Kl[0] + wv * 1024; char* lKb1 = Kl[1] + wv * 1024;
    char* lVb0 = Vl[0] + wv * 1024; char* lVb1 = Vl[1] + wv * 1024;
    {
        GLD(kg + (size_t)srow * 64 + scol, lKb0);
        GLD(kg + (size_t)(32 + srow) * 64 + scol, lKb0 + 4096);
        GLD(vg + (size_t)srow * S_LEN + scol, lVb0);
        GLD(vg + (size_t)(32 + srow) * S_LEN + scol, lVb0 + 4096);
    }
    for (int kt = 0; kt < nkt; ++kt) {
        __syncthreads();
        if (kt + 1 < nkt) {
            int k0n = (kt + 1) * 64;
            char* lK = ((kt + 1) & 1) ? lKb1 : lKb0;
            char* lV = ((kt + 1) & 1) ? lVb1 : lVb0;
            GLD(kg + (size_t)(k0n + srow) * 64 + scol, lK);
            GLD(kg + (size_t)(k0n + 32 + srow) * 64 + scol, lK + 4096);
            GLD(vg + (size_t)srow * S_LEN + k0n + scol, lV);
            GLD(vg + (size_t)(32 + srow) * S_LEN + k0n + scol, lV + 4096);
        }
        if (kt <= mykt) {
            int buf = kt & 1, k0 = kt * 64;
            const char* Kb = Kl[buf];
            const char* Vb = Vl[buf];
            char* Pb = Pl[wv];
            f32x4 sc[2][4] = {};
#pragma unroll
            for (int ct = 0; ct < 4; ++ct) {
                int krow = ct * 16 + lr;
#pragma unroll
                for (int hf = 0; hf < 2; ++hf) {
                    bf16x8 bk = *(const bf16x8*)(Kb + krow * 128 + ((hf * 64 + lg * 16) ^ SWZ(krow)));
#pragma unroll
                    for (int rt = 0; rt < 2; ++rt)
                        sc[rt][ct] = __builtin_amdgcn_mfma_f32_16x16x32_bf16(aq[rt][hf], bk, sc[rt][ct], 0, 0, 0);
                }
            }
            float gb[4]; int kp[4];
#pragma unroll
            for (int ct = 0; ct < 4; ++ct) {
                kp[ct] = k0 + ct * 16 + lr;
                gb[ct] = gs * gate[kp[ct]];
            }
#pragma unroll
            for (int rt = 0; rt < 2; ++rt) {
#pragma unroll
                for (int r = 0; r < 4; ++r) {
                    int q = qbi * 128 + wv * 32 + rt * 16 + lg * 4 + r;
                    float pv[4], vmax = -INFINITY;
#pragma unroll
                    for (int ct = 0; ct < 4; ++ct) {
                        float val = sc[rt][ct][r] + gb[ct];
                        if (kp[ct] > q) val -= 1e9f;
                        pv[ct] = val;
                        vmax = fmaxf(vmax, val);
                    }
                    vmax = fmaxf(vmax, __shfl_xor(vmax, 1));
                    vmax = fmaxf(vmax, __shfl_xor(vmax, 2));
                    vmax = fmaxf(vmax, __shfl_xor(vmax, 4));
                    vmax = fmaxf(vmax, __shfl_xor(vmax, 8));
                    float mn = fmaxf(m_[rt][r], vmax);
                    float scl = __expf(m_[rt][r] - mn);
                    float rs = 0.f;
#pragma unroll
                    for (int ct = 0; ct < 4; ++ct) {
                        float p = __expf(pv[ct] - mn);
                        pv[ct] = p; rs += p;
                    }
                    rs += __shfl_xor(rs, 1); rs += __shfl_xor(rs, 2);
                    rs += __shfl_xor(rs, 4); rs += __shfl_xor(rs, 8);
                    ls_[rt][r] = ls_[rt][r] * scl + rs;
                    m_[rt][r] = mn;
#pragma unroll
                    for (int dt = 0; dt < 4; ++dt) o[rt][dt][r] *= scl;
                    int qloc = rt * 16 + lg * 4 + r;
#pragma unroll
                    for (int ct = 0; ct < 4; ++ct)
                        *(unsigned short*)(Pb + qloc * 128 + (((ct * 16 + lr) * 2) ^ SWZ(qloc))) = f2bf(pv[ct]);
                }
            }
#pragma unroll
            for (int ks = 0; ks < 2; ++ks) {
                bf16x8 pa[2];
#pragma unroll
                for (int rt = 0; rt < 2; ++rt) {
                    int qrow = rt * 16 + lr;
                    pa[rt] = *(const bf16x8*)(Pb + qrow * 128 + ((ks * 64 + lg * 16) ^ SWZ(qrow)));
                }
#pragma unroll
                for (int dt = 0; dt < 4; ++dt) {
                    int vrow = dt * 16 + lr;
                    bf16x8 bv = *(const bf16x8*)(Vb + vrow * 128 + ((ks * 64 + lg * 16) ^ SWZ(vrow)));
#pragma unroll
                    for (int rt = 0; rt < 2; ++rt)
                        o[rt][dt] = __builtin_amdgcn_mfma_f32_16x16x32_bf16(pa[rt], bv, o[rt][dt], 0, 0, 0);
                }
            }
        }
    }
#pragma unroll
    for (int rt = 0; rt < 2; ++rt)
#pragma unroll
        for (int r = 0; r < 4; ++r) {
            float inv = 1.f / ls_[rt][r];
            unsigned short* orow = attnout + (size_t)(qbi * 128 + wv * 32 + rt * 16 + lg * 4 + r) * 2048 + h * 64;
#pragma unroll
            for (int dt = 0; dt < 4; ++dt) orow[dt * 16 + lr] = f2bf(o[rt][dt][r] * inv);
        }
}

extern "C" void kernel_launch(void* const* d_in, const int* in_sizes, int n_in,
                              void* d_out, int out_size, void* d_ws, size_t ws_size,
                              hipStream_t stream) {
    const float* h    = (const float*)d_in[0];
    const float* cosT = (const float*)d_in[2];
    const float* sinT = (const float*)d_in[3];
    const float* Wf   = (const float*)d_in[4];
    const float* W1   = (const float*)d_in[5];
    const float* b1   = (const float*)d_in[6];
    const float* W2   = (const float*)d_in[7];
    const float* b2   = (const float*)d_in[8];
    const float* gs   = (const float*)d_in[9];
    const float* Wq   = (const float*)d_in[10];
    const float* Wk   = (const float*)d_in[11];
    const float* Wv   = (const float*)d_in[12];
    const float* Wo   = (const float*)d_in[13];
    float* out = (float*)d_out;

    char* ws = (char*)d_ws;
    // layout (bytes):
    unsigned short* hb    = (unsigned short*)(ws);                 // 0 .. 8 MiB            [dead after gemm1]
    unsigned short* bt    = (unsigned short*)(ws + 8388608);       // 8388608 .. 21495808   [dead after gemm1]
    float*          qkv   = (float*)(ws + 21495808);               // 21495808 .. 47710208  [dead after rope/vtrans/fuse]
    float*          field = (float*)(ws + 47710208);
    float*          gate  = (float*)(ws + 47718400);
    // aliases over dead regions:
    unsigned short* qbuf    = (unsigned short*)(ws + 8388608);     // 8 MiB  over bt
    unsigned short* kbuf    = (unsigned short*)(ws + 16777216);    // 2 MiB  over bt
    unsigned short* vt      = (unsigned short*)(ws + 18874368);    // 2 MiB  over bt
    unsigned short* wot     = (unsigned short*)(ws + 21495808);    // 8 MiB  over qkv head
    unsigned short* attnout = (unsigned short*)(ws);               // 8 MiB  over hb

    k_cvt_h<<<dim3(4096), dim3(256), 0, stream>>>(h, hb);
    k_transpose<<<dim3(32, 32), dim3(256), 0, stream>>>(Wq, bt, 2048);
    k_transpose<<<dim3(32, 8),  dim3(256), 0, stream>>>(Wk, bt + (size_t)2048 * 2048, 512);
    k_transpose<<<dim3(32, 8),  dim3(256), 0, stream>>>(Wv, bt + (size_t)2560 * 2048, 512);
    k_transpose16<<<dim3(32), dim3(256), 0, stream>>>(Wf, bt + (size_t)3072 * 2048);
    k_transpose<<<dim3(32, 1),  dim3(256), 0, stream>>>(W1, bt + (size_t)3088 * 2048, 64);
    hipMemsetAsync(ws + 8388608 + (size_t)3152 * 4096, 0, (size_t)48 * 4096, stream);
    k_gemm<<<dim3(25, 16), dim3(256), 0, stream>>>(hb, bt, qkv, 2048, NBT, 2048);
    k_rope<<<dim3(2048), dim3(256), 0, stream>>>(qkv, cosT, sinT, qbuf, kbuf);
    k_vtrans<<<dim3(32, 8), dim3(256), 0, stream>>>(qkv, vt);
    k_fuse<<<dim3(512), dim3(256), 0, stream>>>(qkv, W1, b1, W2, b2, field);
    k_gate<<<dim3(1), dim3(256), 0, stream>>>(field, gate);
    k_transpose<<<dim3(32, 32), dim3(256), 0, stream>>>(Wo, wot, 2048);
    k_attn<<<dim3(16, 32), dim3(256), 0, stream>>>(qbuf, kbuf, vt, gate, gs, attnout);
    k_gemm<<<dim3(16, 16), dim3(256), 0, stream>>>(attnout, wot, out, 2048, 2048, 2048);
}